// Round 3
// baseline (112.142 us; speedup 1.0000x reference)
//
#include <hip/hip_runtime.h>
#include <hip/hip_bf16.h>

typedef __bf16 bf16_t;
typedef __bf16 bf16x4 __attribute__((ext_vector_type(4)));
typedef __bf16 bf16x8 __attribute__((ext_vector_type(8)));
typedef float f32x4 __attribute__((ext_vector_type(4)));

#define M_TOT 8192
#define N_TOT 512
#define K_TOT 2048
#define E_TOT 512
#define NSEG  32          // K segments of 64

__device__ __forceinline__ bf16x8 zero8() {
    bf16x8 v;
#pragma unroll
    for (int i = 0; i < 8; ++i) v[i] = (bf16_t)0.0f;
    return v;
}

// ---------------------------------------------------------------------------
// prep4 (unchanged; correctness-proven):
//  blocks [0,256):   LDS-tiled transpose W2[k][n] -> W2t[n][k] bf16
//  blocks [256,288): zb[m][0..8)=cos(theta[q])*cos(x[m,q]) (RX collapse:
//                    |a2|^2-|b2|^2 = cos(theta)*cos(x)); zb[m][8]=1; rest 0
//  blocks [288,296): W1p: permuted W1 rows + bias so h-MFMA C-output lands
//    exactly in main-MFMA A-fragment layout.
//    Row d=(c*2+p)*16+rr holds f = c*32+(rr>>2)*8+p*4+(rr&3).
// ---------------------------------------------------------------------------
__global__ __launch_bounds__(256)
void prep4_kernel(const float* __restrict__ x,
                  const float* __restrict__ theta,
                  const float* __restrict__ W1,
                  const float* __restrict__ b1,
                  const float* __restrict__ W2,
                  bf16_t* __restrict__ W2t,
                  bf16_t* __restrict__ zb,
                  bf16_t* __restrict__ W1p)
{
    const int b = blockIdx.x;
    if (b < 256) {
        __shared__ bf16_t T[64][66];
        const int k0 = (b >> 3) * 64;
        const int n0 = (b & 7) * 64;
        const int kl = threadIdx.x >> 4;
        const int n4 = threadIdx.x & 15;
#pragma unroll
        for (int i = 0; i < 4; ++i) {
            int k = kl + i * 16;
            float4 v = *(const float4*)(W2 + (size_t)(k0 + k) * N_TOT + n0 + n4 * 4);
            T[n4 * 4 + 0][k] = (bf16_t)v.x;
            T[n4 * 4 + 1][k] = (bf16_t)v.y;
            T[n4 * 4 + 2][k] = (bf16_t)v.z;
            T[n4 * 4 + 3][k] = (bf16_t)v.w;
        }
        __syncthreads();
        const int nl = threadIdx.x >> 4;
        const int k4 = threadIdx.x & 15;
#pragma unroll
        for (int i = 0; i < 4; ++i) {
            int n = nl + i * 16;
            bf16x4 v;
            v[0] = T[n][k4 * 4 + 0];
            v[1] = T[n][k4 * 4 + 1];
            v[2] = T[n][k4 * 4 + 2];
            v[3] = T[n][k4 * 4 + 3];
            *(bf16x4*)(W2t + (size_t)(n0 + n) * K_TOT + k0 + k4 * 4) = v;
        }
    } else if (b < 288) {
        const int m = (b - 256) * 256 + threadIdx.x;
        float4 x0 = *(const float4*)(x + (size_t)m * E_TOT);
        float4 x1 = *(const float4*)(x + (size_t)m * E_TOT + 4);
        float xs[8] = {x0.x, x0.y, x0.z, x0.w, x1.x, x1.y, x1.z, x1.w};
        bf16x8 lo;
#pragma unroll
        for (int q = 0; q < 8; ++q)
            lo[q] = (bf16_t)(__builtin_cosf(theta[q]) * __builtin_cosf(xs[q]));
        bf16x8 hi = zero8();
        hi[0] = (bf16_t)1.0f;                  // bias lane at k=8
        *(bf16x8*)(zb + (size_t)m * 16)     = lo;
        *(bf16x8*)(zb + (size_t)m * 16 + 8) = hi;
    } else {
        const int d  = (b - 288) * 256 + threadIdx.x;    // 0..2047
        const int c  = d >> 5;
        const int dd = d & 31;
        const int p  = dd >> 4;
        const int rr = dd & 15;
        const int f  = c * 32 + ((rr >> 2) << 3) + (p << 2) + (rr & 3);
        bf16x8 lo;
#pragma unroll
        for (int q = 0; q < 8; ++q)
            lo[q] = (bf16_t)W1[(size_t)q * K_TOT + f];
        bf16x8 hi = zero8();
        hi[0] = (bf16_t)b1[f];                 // bias at k=8
        *(bf16x8*)(W1p + (size_t)d * 16)     = lo;
        *(bf16x8*)(W1p + (size_t)d * 16 + 8) = hi;
    }
}

// ---------------------------------------------------------------------------
// helpers (128-thread block = 2 waves, block tile 64m x 64n, segment BK=64)
// ---------------------------------------------------------------------------
// B segment: 64n x 64k bf16 = 8KB (one k-tile).
// LDS slot `seg` of row n holds global k-seg g = seg^(n&7)   (same swizzle
// as the proven version; 0 bank conflicts on read and write).
__device__ __forceinline__ void load_B(const bf16_t* __restrict__ W2t, int n_base,
                                       int k0, int t, uint4 gv[4]) {
#pragma unroll
    for (int j = 0; j < 4; ++j) {
        int s    = t + j * 128;        // 0..511
        int n    = (s >> 3) & 63;
        int g    = (s & 7) ^ (n & 7);
        gv[j] = *(const uint4*)(W2t + (size_t)(n_base + n) * K_TOT + k0 + g * 8);
    }
}
__device__ __forceinline__ void write_B(bf16_t* Bb, int t, const uint4 gv[4]) {
#pragma unroll
    for (int j = 0; j < 4; ++j) {
        int s    = t + j * 128;
        int n    = (s >> 3) & 63;
        int seg  = s & 7;
        *(uint4*)(Bb + n * 64 + seg * 8) = gv[j];
    }
}

// W1p frags for one 64-k tile (2 chunks x 2 perm-halves); lanes lq<2 real.
__device__ __forceinline__ void load_wf(const bf16_t* __restrict__ W1p, int k0,
                                        int l15, int lq, bf16x8 wf[4]) {
#pragma unroll
    for (int i = 0; i < 4; ++i) wf[i] = zero8();
    if (lq < 2) {
        const int base = (k0 >> 5) * 2;
#pragma unroll
        for (int i = 0; i < 4; ++i)
            wf[i] = *(const bf16x8*)(W1p + (size_t)((base + i) * 16 + l15) * 16 + lq * 8);
    }
}

// one 64-k tile: B frags from LDS, h in registers (layout-matched MFMA), mains.
// wave tile 32m x 64n: each bfr feeds BOTH mt sub-tiles -> LDS bytes/FLOP
// halved vs the 16m-wave version (this was the R2 bottleneck: 1.07 GB of
// ds_read_b128 = 14-20 us at the LDS ceiling, above the 10.3 us MFMA floor).
// MFMA order per acc register over (s,c) identical -> bit-identical numerics.
__device__ __forceinline__ void compute_tile(const bf16_t* Bb, const bf16x8 wf[4],
                                             const bf16x8 zfrag[2],
                                             int l15, int lq,
                                             f32x4 acc[2][4]) {
    bf16x8 bfr[2][4];
#pragma unroll
    for (int c = 0; c < 2; ++c)
#pragma unroll
        for (int nt = 0; nt < 4; ++nt) {
            int r = nt * 16 + l15;
            int s = (c * 4 + lq) ^ (r & 7);
            bfr[c][nt] = *(const bf16x8*)(Bb + r * 64 + s * 8);
        }

    bf16x8 af[2][2];
#pragma unroll
    for (int mt = 0; mt < 2; ++mt)
#pragma unroll
        for (int c = 0; c < 2; ++c) {
            f32x4 h0 = (f32x4){0.f, 0.f, 0.f, 0.f};
            f32x4 h1 = (f32x4){0.f, 0.f, 0.f, 0.f};
            h0 = __builtin_amdgcn_mfma_f32_16x16x32_bf16(wf[c * 2 + 0], zfrag[mt], h0, 0, 0, 0);
            h1 = __builtin_amdgcn_mfma_f32_16x16x32_bf16(wf[c * 2 + 1], zfrag[mt], h1, 0, 0, 0);
            bf16x8 a;
#pragma unroll
            for (int r = 0; r < 4; ++r) {
                a[r]     = (bf16_t)fmaxf(h0[r], 0.f);
                a[r + 4] = (bf16_t)fmaxf(h1[r], 0.f);
            }
            af[mt][c] = a;
        }

#pragma unroll
    for (int c = 0; c < 2; ++c)
#pragma unroll
        for (int mt = 0; mt < 2; ++mt)
#pragma unroll
            for (int nt = 0; nt < 4; ++nt)
                acc[mt][nt] = __builtin_amdgcn_mfma_f32_16x16x32_bf16(
                    af[mt][c], bfr[c][nt], acc[mt][nt], 0, 0, 0);
}

// ---------------------------------------------------------------------------
// Fused GEMM: out = relu(z@W1+b1) @ W2 + b2
// Block 64m x 64n, 128 thr = 2 waves (2m x 1n), wave 32m x 64n.
// Grid 1024 = 8 blocks/CU -> 16 waves/CU (4/SIMD): same TLP as R2 but each
// wave has 2x the FLOPs per LDS byte (32 m-rows per wave).
// BK=64 segments, double-buffered (2 x 8KB LDS = 16KB/block -> 128KB/CU),
// ONE barrier per segment (write buf[1-cur] after compute; next top-of-loop
// barrier publishes it). h entirely in registers via layout-matched h-MFMA.
// ---------------------------------------------------------------------------
__global__ __launch_bounds__(128, 4)
void ffq_gemm_kernel(const bf16_t* __restrict__ zb,    // [8192][16]
                     const bf16_t* __restrict__ W1p,   // [2048][16] permuted
                     const bf16_t* __restrict__ W2t,   // [512][2048]
                     const float* __restrict__ b2,
                     float* __restrict__ out)          // [8192][512]
{
    __shared__ bf16_t Blds[2][64 * 64];   // 2 bufs x one 64n x 64k tile

    const int t = threadIdx.x;            // 0..127
    const int w = t >> 6, l = t & 63;     // w in {0,1}: m-slot of 32
    const int m_base = blockIdx.y * 64;
    const int n_base = blockIdx.x * 64;
    const int l15 = l & 15, lq = l >> 4;

    // persistent z^T B-frags for this wave's two 16-row m-tiles
    bf16x8 zfrag[2];
#pragma unroll
    for (int mt = 0; mt < 2; ++mt) {
        zfrag[mt] = zero8();
        if (lq < 2)
            zfrag[mt] = *(const bf16x8*)(zb + (size_t)(m_base + w * 32 + mt * 16 + l15) * 16 + lq * 8);
    }

    f32x4 acc[2][4];
#pragma unroll
    for (int mt = 0; mt < 2; ++mt)
#pragma unroll
        for (int nt = 0; nt < 4; ++nt)
            acc[mt][nt] = (f32x4){0.f, 0.f, 0.f, 0.f};

    uint4 gv[4];

    // prologue: segment 0 -> buf0
    load_B(W2t, n_base, 0, t, gv);
    write_B(Blds[0], t, gv);

    for (int s = 0; s < NSEG; ++s) {
        const int cur = s & 1;
        __syncthreads();                               // publish buf[cur]
        if (s + 1 < NSEG) load_B(W2t, n_base, (s + 1) * 64, t, gv);

        bf16x8 wf[4];
        load_wf(W1p, s * 64, l15, lq, wf);
        compute_tile(Blds[cur], wf, zfrag, l15, lq, acc);

        if (s + 1 < NSEG) write_B(Blds[1 - cur], t, gv);   // precise vmcnt
    }

    // ---- epilogue: C/D layout col=lane&15, row=(lane>>4)*4+r ----
#pragma unroll
    for (int nt = 0; nt < 4; ++nt) {
        int col = n_base + nt * 16 + l15;
        float bias = b2[col];
#pragma unroll
        for (int mt = 0; mt < 2; ++mt) {
#pragma unroll
            for (int r = 0; r < 4; ++r) {
                int row = m_base + w * 32 + mt * 16 + lq * 4 + r;
                out[(size_t)row * N_TOT + col] = acc[mt][nt][r] + bias;
            }
        }
    }
}

extern "C" void kernel_launch(void* const* d_in, const int* in_sizes, int n_in,
                              void* d_out, int out_size, void* d_ws, size_t ws_size,
                              hipStream_t stream) {
    const float* x     = (const float*)d_in[0];
    const float* theta = (const float*)d_in[1];
    const float* W1    = (const float*)d_in[2];
    const float* b1    = (const float*)d_in[3];
    const float* W2    = (const float*)d_in[4];
    const float* b2    = (const float*)d_in[5];
    float* out = (float*)d_out;

    // ws: [0,2MB) W2t ; [2MB,2.25MB) zb[8192][16] ; then W1p[2048][16]
    const size_t W2T_BYTES = (size_t)N_TOT * K_TOT * sizeof(bf16_t);  // 2 MB
    const size_t ZB_BYTES  = (size_t)M_TOT * 16 * sizeof(bf16_t);     // 256 KB

    bf16_t* W2t = (bf16_t*)d_ws;
    bf16_t* zb  = (bf16_t*)((char*)d_ws + W2T_BYTES);
    bf16_t* W1p = (bf16_t*)((char*)d_ws + W2T_BYTES + ZB_BYTES);

    prep4_kernel<<<296, 256, 0, stream>>>(x, theta, W1, b1, W2, W2t, zb, W1p);

    dim3 grid(N_TOT / 64, M_TOT / 64);    // (8, 128) = 1024 blocks, 8/CU
    ffq_gemm_kernel<<<grid, 128, 0, stream>>>(zb, W1p, W2t, b2, out);
}

// Round 4
// 108.919 us; speedup vs baseline: 1.0296x; 1.0296x over previous
//
#include <hip/hip_runtime.h>
#include <hip/hip_bf16.h>

typedef __bf16 bf16_t;
typedef __bf16 bf16x4 __attribute__((ext_vector_type(4)));
typedef __bf16 bf16x8 __attribute__((ext_vector_type(8)));
typedef float f32x4 __attribute__((ext_vector_type(4)));

#define M_TOT 8192
#define N_TOT 512
#define K_TOT 2048
#define E_TOT 512
#define NSEG  16          // K segments of 128

__device__ __forceinline__ bf16x8 zero8() {
    bf16x8 v;
#pragma unroll
    for (int i = 0; i < 8; ++i) v[i] = (bf16_t)0.0f;
    return v;
}

// ---------------------------------------------------------------------------
// prep4 (unchanged; correctness-proven):
//  blocks [0,256):   LDS-tiled transpose W2[k][n] -> W2t[n][k] bf16
//  blocks [256,288): zb[m][0..8)=cos(theta[q])*cos(x[m,q]) (RX collapse:
//                    |a2|^2-|b2|^2 = cos(theta)*cos(x)); zb[m][8]=1; rest 0
//  blocks [288,296): W1p: permuted W1 rows + bias so h-MFMA C-output lands
//    exactly in main-MFMA A-fragment layout.
//    Row d=(c*2+p)*16+rr holds f = c*32+(rr>>2)*8+p*4+(rr&3).
// ---------------------------------------------------------------------------
__global__ __launch_bounds__(256)
void prep4_kernel(const float* __restrict__ x,
                  const float* __restrict__ theta,
                  const float* __restrict__ W1,
                  const float* __restrict__ b1,
                  const float* __restrict__ W2,
                  bf16_t* __restrict__ W2t,
                  bf16_t* __restrict__ zb,
                  bf16_t* __restrict__ W1p)
{
    const int b = blockIdx.x;
    if (b < 256) {
        __shared__ bf16_t T[64][66];
        const int k0 = (b >> 3) * 64;
        const int n0 = (b & 7) * 64;
        const int kl = threadIdx.x >> 4;
        const int n4 = threadIdx.x & 15;
#pragma unroll
        for (int i = 0; i < 4; ++i) {
            int k = kl + i * 16;
            float4 v = *(const float4*)(W2 + (size_t)(k0 + k) * N_TOT + n0 + n4 * 4);
            T[n4 * 4 + 0][k] = (bf16_t)v.x;
            T[n4 * 4 + 1][k] = (bf16_t)v.y;
            T[n4 * 4 + 2][k] = (bf16_t)v.z;
            T[n4 * 4 + 3][k] = (bf16_t)v.w;
        }
        __syncthreads();
        const int nl = threadIdx.x >> 4;
        const int k4 = threadIdx.x & 15;
#pragma unroll
        for (int i = 0; i < 4; ++i) {
            int n = nl + i * 16;
            bf16x4 v;
            v[0] = T[n][k4 * 4 + 0];
            v[1] = T[n][k4 * 4 + 1];
            v[2] = T[n][k4 * 4 + 2];
            v[3] = T[n][k4 * 4 + 3];
            *(bf16x4*)(W2t + (size_t)(n0 + n) * K_TOT + k0 + k4 * 4) = v;
        }
    } else if (b < 288) {
        const int m = (b - 256) * 256 + threadIdx.x;
        float4 x0 = *(const float4*)(x + (size_t)m * E_TOT);
        float4 x1 = *(const float4*)(x + (size_t)m * E_TOT + 4);
        float xs[8] = {x0.x, x0.y, x0.z, x0.w, x1.x, x1.y, x1.z, x1.w};
        bf16x8 lo;
#pragma unroll
        for (int q = 0; q < 8; ++q)
            lo[q] = (bf16_t)(__builtin_cosf(theta[q]) * __builtin_cosf(xs[q]));
        bf16x8 hi = zero8();
        hi[0] = (bf16_t)1.0f;                  // bias lane at k=8
        *(bf16x8*)(zb + (size_t)m * 16)     = lo;
        *(bf16x8*)(zb + (size_t)m * 16 + 8) = hi;
    } else {
        const int d  = (b - 288) * 256 + threadIdx.x;    // 0..2047
        const int c  = d >> 5;
        const int dd = d & 31;
        const int p  = dd >> 4;
        const int rr = dd & 15;
        const int f  = c * 32 + ((rr >> 2) << 3) + (p << 2) + (rr & 3);
        bf16x8 lo;
#pragma unroll
        for (int q = 0; q < 8; ++q)
            lo[q] = (bf16_t)W1[(size_t)q * K_TOT + f];
        bf16x8 hi = zero8();
        hi[0] = (bf16_t)b1[f];                 // bias at k=8
        *(bf16x8*)(W1p + (size_t)d * 16)     = lo;
        *(bf16x8*)(W1p + (size_t)d * 16 + 8) = hi;
    }
}

// ---------------------------------------------------------------------------
// helpers (128-thread block = 2 waves, block tile 64m x 64n, segment BK=128)
// ---------------------------------------------------------------------------
// B segment: 64n x 128k bf16 = 16KB, as two 64x64 k-tiles. LDS byte layout is
// LINEAR in s (byte = s*16, s=0..1023): tile=s>>9, n=(s>>3)&63, seg=s&7.
// The XOR swizzle (slot seg holds global k-chunk g=seg^(n&7)) is applied on
// the GLOBAL source address, LDS dest stays linear -> global_load_lds legal
// (wave-uniform base + lane*16), and the swizzled ds_read side is unchanged.
__device__ __forceinline__ void stage_B(const bf16_t* __restrict__ W2t,
                                        bf16_t* dst_buf, int n_base, int k0,
                                        int w, int l) {
#pragma unroll
    for (int j = 0; j < 8; ++j) {
        int s    = w * 64 + l + j * 128;   // this lane's 16B slot
        int tile = s >> 9;
        int n    = (s >> 3) & 63;
        int g    = (s & 7) ^ (n & 7);
        const bf16_t* src = W2t + (size_t)(n_base + n) * K_TOT
                            + k0 + tile * 64 + g * 8;
        // wave-uniform LDS base for (w,j); HW adds lane*16 -> byte s*16
        bf16_t* ldst = dst_buf + (size_t)(w * 64 + j * 128) * 8;
        __builtin_amdgcn_global_load_lds(
            (const __attribute__((address_space(1))) unsigned int*)src,
            (__attribute__((address_space(3))) unsigned int*)ldst,
            16, 0, 0);
    }
}

// W1p frags for one 64-k tile (2 chunks x 2 perm-halves); lanes lq<2 real.
__device__ __forceinline__ void load_wf(const bf16_t* __restrict__ W1p, int k0,
                                        int l15, int lq, bf16x8 wf[4]) {
#pragma unroll
    for (int i = 0; i < 4; ++i) wf[i] = zero8();
    if (lq < 2) {
        const int base = (k0 >> 5) * 2;
#pragma unroll
        for (int i = 0; i < 4; ++i)
            wf[i] = *(const bf16x8*)(W1p + (size_t)((base + i) * 16 + l15) * 16 + lq * 8);
    }
}

// one 64-k tile: B frags from LDS, h in registers (layout-matched MFMA), mains.
// wave tile 32m x 64n: each bfr feeds BOTH mt sub-tiles.
// MFMA order per acc register over (k-chunk) identical to the proven
// version -> bit-identical numerics.
__device__ __forceinline__ void compute_tile(const bf16_t* Bb, const bf16x8 wf[4],
                                             const bf16x8 zfrag[2],
                                             int l15, int lq,
                                             f32x4 acc[2][4]) {
    bf16x8 bfr[2][4];
#pragma unroll
    for (int c = 0; c < 2; ++c)
#pragma unroll
        for (int nt = 0; nt < 4; ++nt) {
            int r = nt * 16 + l15;
            int s = (c * 4 + lq) ^ (r & 7);
            bfr[c][nt] = *(const bf16x8*)(Bb + r * 64 + s * 8);
        }

    bf16x8 af[2][2];
#pragma unroll
    for (int mt = 0; mt < 2; ++mt)
#pragma unroll
        for (int c = 0; c < 2; ++c) {
            f32x4 h0 = (f32x4){0.f, 0.f, 0.f, 0.f};
            f32x4 h1 = (f32x4){0.f, 0.f, 0.f, 0.f};
            h0 = __builtin_amdgcn_mfma_f32_16x16x32_bf16(wf[c * 2 + 0], zfrag[mt], h0, 0, 0, 0);
            h1 = __builtin_amdgcn_mfma_f32_16x16x32_bf16(wf[c * 2 + 1], zfrag[mt], h1, 0, 0, 0);
            bf16x8 a;
#pragma unroll
            for (int r = 0; r < 4; ++r) {
                a[r]     = (bf16_t)fmaxf(h0[r], 0.f);
                a[r + 4] = (bf16_t)fmaxf(h1[r], 0.f);
            }
            af[mt][c] = a;
        }

#pragma unroll
    for (int c = 0; c < 2; ++c)
#pragma unroll
        for (int mt = 0; mt < 2; ++mt)
#pragma unroll
            for (int nt = 0; nt < 4; ++nt)
                acc[mt][nt] = __builtin_amdgcn_mfma_f32_16x16x32_bf16(
                    af[mt][c], bfr[c][nt], acc[mt][nt], 0, 0, 0);
}

// ---------------------------------------------------------------------------
// Fused GEMM: out = relu(z@W1+b1) @ W2 + b2
// Block 64m x 64n, 128 thr = 2 waves, wave 32m x 64n (low LDS bytes/FLOP).
// Grid (8,128)=1024 -> 4 blocks/CU, 8 waves/CU; barriers of the 4 blocks
// are independent -> decorrelated stalls across the CU.
// BK=128 segments (16 barriers total), double-buffered 2 x 16KB LDS.
// B staging via global_load_lds width=16 (async direct-to-LDS, no VGPR
// round-trip): loads for segment s+1 issue right after the top barrier and
// drain only at the NEXT barrier's implicit vmcnt(0) -- one full segment of
// MFMA work in between. This targets the ~600 TF issue-rate plateau of the
// reg-staged 2-barrier structure (m93->m97 ladder: +69% from this change).
// h entirely in registers via layout-matched h-MFMA (permuted W1p).
// ---------------------------------------------------------------------------
__global__ __launch_bounds__(128, 2)
void ffq_gemm_kernel(const bf16_t* __restrict__ zb,    // [8192][16]
                     const bf16_t* __restrict__ W1p,   // [2048][16] permuted
                     const bf16_t* __restrict__ W2t,   // [512][2048]
                     const float* __restrict__ b2,
                     float* __restrict__ out)          // [8192][512]
{
    __shared__ bf16_t Blds[2][2 * 64 * 64];   // 2 bufs x (two 64x64 k-tiles)

    const int t = threadIdx.x;            // 0..127
    const int w = t >> 6, l = t & 63;     // w in {0,1}: m-slot of 32
    const int m_base = blockIdx.y * 64;
    const int n_base = blockIdx.x * 64;
    const int l15 = l & 15, lq = l >> 4;

    // persistent z^T B-frags for this wave's two 16-row m-tiles
    bf16x8 zfrag[2];
#pragma unroll
    for (int mt = 0; mt < 2; ++mt) {
        zfrag[mt] = zero8();
        if (lq < 2)
            zfrag[mt] = *(const bf16x8*)(zb + (size_t)(m_base + w * 32 + mt * 16 + l15) * 16 + lq * 8);
    }

    f32x4 acc[2][4];
#pragma unroll
    for (int mt = 0; mt < 2; ++mt)
#pragma unroll
        for (int nt = 0; nt < 4; ++nt)
            acc[mt][nt] = (f32x4){0.f, 0.f, 0.f, 0.f};

    // prologue: segment 0 -> buf0 (async; first barrier drains+publishes)
    stage_B(W2t, Blds[0], n_base, 0, w, l);

    for (int s = 0; s < NSEG; ++s) {
        const int cur = s & 1;
        __syncthreads();                   // vmcnt(0) drain + publish buf[cur]
        if (s + 1 < NSEG)
            stage_B(W2t, Blds[1 - cur], n_base, (s + 1) * 128, w, l);

#pragma unroll
        for (int tt = 0; tt < 2; ++tt) {
            bf16x8 wf[4];
            load_wf(W1p, s * 128 + tt * 64, l15, lq, wf);
            compute_tile(Blds[cur] + tt * 4096, wf, zfrag, l15, lq, acc);
        }
    }

    // ---- epilogue: C/D layout col=lane&15, row=(lane>>4)*4+r ----
#pragma unroll
    for (int nt = 0; nt < 4; ++nt) {
        int col = n_base + nt * 16 + l15;
        float bias = b2[col];
#pragma unroll
        for (int mt = 0; mt < 2; ++mt) {
#pragma unroll
            for (int r = 0; r < 4; ++r) {
                int row = m_base + w * 32 + mt * 16 + lq * 4 + r;
                out[(size_t)row * N_TOT + col] = acc[mt][nt][r] + bias;
            }
        }
    }
}

extern "C" void kernel_launch(void* const* d_in, const int* in_sizes, int n_in,
                              void* d_out, int out_size, void* d_ws, size_t ws_size,
                              hipStream_t stream) {
    const float* x     = (const float*)d_in[0];
    const float* theta = (const float*)d_in[1];
    const float* W1    = (const float*)d_in[2];
    const float* b1    = (const float*)d_in[3];
    const float* W2    = (const float*)d_in[4];
    const float* b2    = (const float*)d_in[5];
    float* out = (float*)d_out;

    // ws: [0,2MB) W2t ; [2MB,2.25MB) zb[8192][16] ; then W1p[2048][16]
    const size_t W2T_BYTES = (size_t)N_TOT * K_TOT * sizeof(bf16_t);  // 2 MB
    const size_t ZB_BYTES  = (size_t)M_TOT * 16 * sizeof(bf16_t);     // 256 KB

    bf16_t* W2t = (bf16_t*)d_ws;
    bf16_t* zb  = (bf16_t*)((char*)d_ws + W2T_BYTES);
    bf16_t* W1p = (bf16_t*)((char*)d_ws + W2T_BYTES + ZB_BYTES);

    prep4_kernel<<<296, 256, 0, stream>>>(x, theta, W1, b1, W2, W2t, zb, W1p);

    dim3 grid(N_TOT / 64, M_TOT / 64);    // (8, 128) = 1024 blocks, 4/CU
    ffq_gemm_kernel<<<grid, 128, 0, stream>>>(zb, W1p, W2t, b2, out);
}

// Round 5
// 102.453 us; speedup vs baseline: 1.0946x; 1.0631x over previous
//
#include <hip/hip_runtime.h>
#include <hip/hip_bf16.h>

typedef __bf16 bf16_t;
typedef __bf16 bf16x4 __attribute__((ext_vector_type(4)));
typedef __bf16 bf16x8 __attribute__((ext_vector_type(8)));
typedef float f32x4 __attribute__((ext_vector_type(4)));

#define M_TOT 8192
#define N_TOT 512
#define K_TOT 2048
#define E_TOT 512
#define NSEG_HALF 8       // 8 segments of BK=128 per k-slice (K=2048 split x2)

__device__ __forceinline__ bf16x8 zero8() {
    bf16x8 v;
#pragma unroll
    for (int i = 0; i < 8; ++i) v[i] = (bf16_t)0.0f;
    return v;
}

// ---------------------------------------------------------------------------
// prep4 (unchanged; correctness-proven):
//  blocks [0,256):   LDS-tiled transpose W2[k][n] -> W2t[n][k] bf16
//  blocks [256,288): zb[m][0..8)=cos(theta[q])*cos(x[m,q]) (RX collapse:
//                    |a2|^2-|b2|^2 = cos(theta)*cos(x)); zb[m][8]=1; rest 0
//  blocks [288,296): W1p: permuted W1 rows + bias so h-MFMA C-output lands
//    exactly in main-MFMA A-fragment layout.
//    Row d=(c*2+p)*16+rr holds f = c*32+(rr>>2)*8+p*4+(rr&3).
// ---------------------------------------------------------------------------
__global__ __launch_bounds__(256)
void prep4_kernel(const float* __restrict__ x,
                  const float* __restrict__ theta,
                  const float* __restrict__ W1,
                  const float* __restrict__ b1,
                  const float* __restrict__ W2,
                  bf16_t* __restrict__ W2t,
                  bf16_t* __restrict__ zb,
                  bf16_t* __restrict__ W1p)
{
    const int b = blockIdx.x;
    if (b < 256) {
        __shared__ bf16_t T[64][66];
        const int k0 = (b >> 3) * 64;
        const int n0 = (b & 7) * 64;
        const int kl = threadIdx.x >> 4;
        const int n4 = threadIdx.x & 15;
#pragma unroll
        for (int i = 0; i < 4; ++i) {
            int k = kl + i * 16;
            float4 v = *(const float4*)(W2 + (size_t)(k0 + k) * N_TOT + n0 + n4 * 4);
            T[n4 * 4 + 0][k] = (bf16_t)v.x;
            T[n4 * 4 + 1][k] = (bf16_t)v.y;
            T[n4 * 4 + 2][k] = (bf16_t)v.z;
            T[n4 * 4 + 3][k] = (bf16_t)v.w;
        }
        __syncthreads();
        const int nl = threadIdx.x >> 4;
        const int k4 = threadIdx.x & 15;
#pragma unroll
        for (int i = 0; i < 4; ++i) {
            int n = nl + i * 16;
            bf16x4 v;
            v[0] = T[n][k4 * 4 + 0];
            v[1] = T[n][k4 * 4 + 1];
            v[2] = T[n][k4 * 4 + 2];
            v[3] = T[n][k4 * 4 + 3];
            *(bf16x4*)(W2t + (size_t)(n0 + n) * K_TOT + k0 + k4 * 4) = v;
        }
    } else if (b < 288) {
        const int m = (b - 256) * 256 + threadIdx.x;
        float4 x0 = *(const float4*)(x + (size_t)m * E_TOT);
        float4 x1 = *(const float4*)(x + (size_t)m * E_TOT + 4);
        float xs[8] = {x0.x, x0.y, x0.z, x0.w, x1.x, x1.y, x1.z, x1.w};
        bf16x8 lo;
#pragma unroll
        for (int q = 0; q < 8; ++q)
            lo[q] = (bf16_t)(__builtin_cosf(theta[q]) * __builtin_cosf(xs[q]));
        bf16x8 hi = zero8();
        hi[0] = (bf16_t)1.0f;                  // bias lane at k=8
        *(bf16x8*)(zb + (size_t)m * 16)     = lo;
        *(bf16x8*)(zb + (size_t)m * 16 + 8) = hi;
    } else {
        const int d  = (b - 288) * 256 + threadIdx.x;    // 0..2047
        const int c  = d >> 5;
        const int dd = d & 31;
        const int p  = dd >> 4;
        const int rr = dd & 15;
        const int f  = c * 32 + ((rr >> 2) << 3) + (p << 2) + (rr & 3);
        bf16x8 lo;
#pragma unroll
        for (int q = 0; q < 8; ++q)
            lo[q] = (bf16_t)W1[(size_t)q * K_TOT + f];
        bf16x8 hi = zero8();
        hi[0] = (bf16_t)b1[f];                 // bias at k=8
        *(bf16x8*)(W1p + (size_t)d * 16)     = lo;
        *(bf16x8*)(W1p + (size_t)d * 16 + 8) = hi;
    }
}

// ---------------------------------------------------------------------------
// helpers (512-thread block = 8 waves: 4 m-slots x 2 k-slices;
//          block tile 128m x 64n, per-slice segment BK=128)
// ---------------------------------------------------------------------------
// B segment: 64n x 128k bf16 = 16KB, as two 64x64 k-tiles. LDS byte layout is
// LINEAR in s (byte = s*16, s=0..1023): tile=s>>9, n=(s>>3)&63, seg=s&7.
// The XOR swizzle (slot seg holds global k-chunk g=seg^(n&7)) is applied on
// the GLOBAL source address, LDS dest stays linear -> global_load_lds legal
// (wave-uniform base + lane*16); swizzled ds_read side unchanged.
// Staged by the k-slice's own 256 threads (4 waves x 4 slots).
__device__ __forceinline__ void stage_B(const bf16_t* __restrict__ W2t,
                                        bf16_t* dst_buf, int n_base, int k0,
                                        int wl, int l) {
#pragma unroll
    for (int j = 0; j < 4; ++j) {
        int s    = wl * 64 + l + j * 256;  // this lane's 16B slot (0..1023)
        int tile = s >> 9;
        int n    = (s >> 3) & 63;
        int g    = (s & 7) ^ (n & 7);
        const bf16_t* src = W2t + (size_t)(n_base + n) * K_TOT
                            + k0 + tile * 64 + g * 8;
        // wave-uniform LDS base for (wl,j); HW adds lane*16 -> byte s*16
        bf16_t* ldst = dst_buf + (size_t)(wl * 64 + j * 256) * 8;
        __builtin_amdgcn_global_load_lds(
            (const __attribute__((address_space(1))) unsigned int*)src,
            (__attribute__((address_space(3))) unsigned int*)ldst,
            16, 0, 0);
    }
}

// W1p frags for one 64-k tile (2 chunks x 2 perm-halves); lanes lq<2 real.
// k0 is the ABSOLUTE k offset (works for either k-slice).
__device__ __forceinline__ void load_wf(const bf16_t* __restrict__ W1p, int k0,
                                        int l15, int lq, bf16x8 wf[4]) {
#pragma unroll
    for (int i = 0; i < 4; ++i) wf[i] = zero8();
    if (lq < 2) {
        const int base = (k0 >> 5) * 2;
#pragma unroll
        for (int i = 0; i < 4; ++i)
            wf[i] = *(const bf16x8*)(W1p + (size_t)((base + i) * 16 + l15) * 16 + lq * 8);
    }
}

// one 64-k tile: B frags from LDS, h in registers (layout-matched MFMA), mains.
// wave tile 32m x 64n: each bfr feeds BOTH mt sub-tiles (low LDS bytes/FLOP).
// MFMA order per acc register over (k-chunk) identical within a slice.
__device__ __forceinline__ void compute_tile(const bf16_t* Bb, const bf16x8 wf[4],
                                             const bf16x8 zfrag[2],
                                             int l15, int lq,
                                             f32x4 acc[2][4]) {
    bf16x8 bfr[2][4];
#pragma unroll
    for (int c = 0; c < 2; ++c)
#pragma unroll
        for (int nt = 0; nt < 4; ++nt) {
            int r = nt * 16 + l15;
            int s = (c * 4 + lq) ^ (r & 7);
            bfr[c][nt] = *(const bf16x8*)(Bb + r * 64 + s * 8);
        }

    bf16x8 af[2][2];
#pragma unroll
    for (int mt = 0; mt < 2; ++mt)
#pragma unroll
        for (int c = 0; c < 2; ++c) {
            f32x4 h0 = (f32x4){0.f, 0.f, 0.f, 0.f};
            f32x4 h1 = (f32x4){0.f, 0.f, 0.f, 0.f};
            h0 = __builtin_amdgcn_mfma_f32_16x16x32_bf16(wf[c * 2 + 0], zfrag[mt], h0, 0, 0, 0);
            h1 = __builtin_amdgcn_mfma_f32_16x16x32_bf16(wf[c * 2 + 1], zfrag[mt], h1, 0, 0, 0);
            bf16x8 a;
#pragma unroll
            for (int r = 0; r < 4; ++r) {
                a[r]     = (bf16_t)fmaxf(h0[r], 0.f);
                a[r + 4] = (bf16_t)fmaxf(h1[r], 0.f);
            }
            af[mt][c] = a;
        }

#pragma unroll
    for (int c = 0; c < 2; ++c)
#pragma unroll
        for (int mt = 0; mt < 2; ++mt)
#pragma unroll
            for (int nt = 0; nt < 4; ++nt)
                acc[mt][nt] = __builtin_amdgcn_mfma_f32_16x16x32_bf16(
                    af[mt][c], bfr[c][nt], acc[mt][nt], 0, 0, 0);
}

// ---------------------------------------------------------------------------
// Fused GEMM: out = relu(z@W1+b1) @ W2 + b2
// Block 128m x 64n, 512 thr = 8 waves = 4 m-slots (32m each) x 2 K-SLICES.
// Split-K x2 inside the block: slice ks handles k in [ks*1024,(ks+1)*1024),
// each with its own independent double-buffered 8-segment pipeline
// (LDS 2 slices x 2 bufs x 16KB = 64KB/block). Final combine through LDS
// (slice1 dumps f32 partials, slice0 adds + bias + store) -- deterministic,
// no atomics.
// Grid (8,64)=512 blocks = 2 blocks/CU -> 16 waves/CU (4/SIMD): combines
// R2's winning TLP with the 32m-wave's halved LDS bytes/FLOP (512MB total
// ds_read -> 7.4us floor, under the 10.3us MFMA floor).
// B staging via global_load_lds width=16 (async direct-to-LDS): loads for
// segment s+1 issue right after the top barrier, drain at the next barrier.
// h entirely in registers via layout-matched h-MFMA (permuted W1p).
// ---------------------------------------------------------------------------
__global__ __launch_bounds__(512, 4)
void ffq_gemm_kernel(const bf16_t* __restrict__ zb,    // [8192][16]
                     const bf16_t* __restrict__ W1p,   // [2048][16] permuted
                     const bf16_t* __restrict__ W2t,   // [512][2048]
                     const float* __restrict__ b2,
                     float* __restrict__ out)          // [8192][512]
{
    __shared__ bf16_t Blds[2][2][2 * 64 * 64];  // [kslice][buf][two 64x64 tiles]

    const int t  = threadIdx.x;           // 0..511
    const int w  = t >> 6, l = t & 63;
    const int ks = w >> 2;                // k-slice 0/1
    const int wl = w & 3;                 // m-slot of 32 rows
    const int m_base = blockIdx.y * 128;
    const int n_base = blockIdx.x * 64;
    const int l15 = l & 15, lq = l >> 4;
    const int k_base = ks * 1024;

    // persistent z^T B-frags for this wave's two 16-row m-tiles
    bf16x8 zfrag[2];
#pragma unroll
    for (int mt = 0; mt < 2; ++mt) {
        zfrag[mt] = zero8();
        if (lq < 2)
            zfrag[mt] = *(const bf16x8*)(zb + (size_t)(m_base + wl * 32 + mt * 16 + l15) * 16 + lq * 8);
    }

    f32x4 acc[2][4];
#pragma unroll
    for (int mt = 0; mt < 2; ++mt)
#pragma unroll
        for (int nt = 0; nt < 4; ++nt)
            acc[mt][nt] = (f32x4){0.f, 0.f, 0.f, 0.f};

    // prologue: this slice's segment 0 -> buf0 (async; first barrier drains)
    stage_B(W2t, Blds[ks][0], n_base, k_base, wl, l);

    for (int s = 0; s < NSEG_HALF; ++s) {
        const int cur = s & 1;
        __syncthreads();                   // vmcnt(0) drain + publish buf[cur]
        if (s + 1 < NSEG_HALF)
            stage_B(W2t, Blds[ks][1 - cur], n_base, k_base + (s + 1) * 128, wl, l);

#pragma unroll
        for (int tt = 0; tt < 2; ++tt) {
            bf16x8 wf[4];
            load_wf(W1p, k_base + s * 128 + tt * 64, l15, lq, wf);
            compute_tile(Blds[ks][cur] + tt * 4096, wf, zfrag, l15, lq, acc);
        }
    }

    // ---- split-K combine through LDS (reuse Blds as f32 scratch) ----
    __syncthreads();                       // all LDS reads of B done
    float* F = (float*)&Blds[0][0][0];     // 32KB needed, 64KB available
    if (ks == 1) {
#pragma unroll
        for (int mt = 0; mt < 2; ++mt)
#pragma unroll
            for (int nt = 0; nt < 4; ++nt) {
                int idx = ((wl * 2 + mt) * 4 + nt) * 64 + l;   // lane-contig 16B
                *(f32x4*)(F + (size_t)idx * 4) = acc[mt][nt];
            }
    }
    __syncthreads();
    if (ks == 0) {
        // ---- epilogue: C/D layout col=lane&15, row=(lane>>4)*4+r ----
#pragma unroll
        for (int nt = 0; nt < 4; ++nt) {
            int col = n_base + nt * 16 + l15;
            float bias = b2[col];
#pragma unroll
            for (int mt = 0; mt < 2; ++mt) {
                int idx = ((wl * 2 + mt) * 4 + nt) * 64 + l;
                f32x4 part = *(const f32x4*)(F + (size_t)idx * 4);
#pragma unroll
                for (int r = 0; r < 4; ++r) {
                    int row = m_base + wl * 32 + mt * 16 + lq * 4 + r;
                    out[(size_t)row * N_TOT + col] = acc[mt][nt][r] + part[r] + bias;
                }
            }
        }
    }
}

extern "C" void kernel_launch(void* const* d_in, const int* in_sizes, int n_in,
                              void* d_out, int out_size, void* d_ws, size_t ws_size,
                              hipStream_t stream) {
    const float* x     = (const float*)d_in[0];
    const float* theta = (const float*)d_in[1];
    const float* W1    = (const float*)d_in[2];
    const float* b1    = (const float*)d_in[3];
    const float* W2    = (const float*)d_in[4];
    const float* b2    = (const float*)d_in[5];
    float* out = (float*)d_out;

    // ws: [0,2MB) W2t ; [2MB,2.25MB) zb[8192][16] ; then W1p[2048][16]
    const size_t W2T_BYTES = (size_t)N_TOT * K_TOT * sizeof(bf16_t);  // 2 MB
    const size_t ZB_BYTES  = (size_t)M_TOT * 16 * sizeof(bf16_t);     // 256 KB

    bf16_t* W2t = (bf16_t*)d_ws;
    bf16_t* zb  = (bf16_t*)((char*)d_ws + W2T_BYTES);
    bf16_t* W1p = (bf16_t*)((char*)d_ws + W2T_BYTES + ZB_BYTES);

    prep4_kernel<<<296, 256, 0, stream>>>(x, theta, W1, b1, W2, W2t, zb, W1p);

    dim3 grid(N_TOT / 64, M_TOT / 128);   // (8, 64) = 512 blocks, 2/CU
    ffq_gemm_kernel<<<grid, 512, 0, stream>>>(zb, W1p, W2t, b2, out);
}